// Round 10
// baseline (237.258 us; speedup 1.0000x reference)
//
#include <hip/hip_runtime.h>
#include <math.h>

// B=2, T=2048, DIM=1024, H=16, HD=64. Inputs fp32, output fp32.
// R9: S^T attn = 64.4us; V b64 reads 4-way bank-conflicted (4.2e6) + barrier
// drains DMA with zero overlap. R10: (1) V staged via precomputed LDS-image
// (prep writes the exact DMA byte order -> lane-linear reads, conflict-free);
// (2) double-buffered K/V LDS, prefetch issued after barrier -> DMA overlaps
// the full compute phase.

typedef unsigned short u16;
typedef __attribute__((ext_vector_type(8))) short short8;
typedef __attribute__((ext_vector_type(4))) short short4v;
typedef __attribute__((ext_vector_type(4))) float f32x4;
typedef __attribute__((ext_vector_type(16))) float f32x16;

#define T_SEQ 2048

__device__ __forceinline__ float b2f(u16 u) {
    union { unsigned int i; float f; } x; x.i = ((unsigned int)u) << 16; return x.f;
}
__device__ __forceinline__ u16 f2b(float f) {
    union { float f; unsigned int i; } x; x.f = f;
    return (u16)((x.i + 0x7FFFu + ((x.i >> 16) & 1u)) >> 16);  // RNE
}
__device__ __forceinline__ void gl_lds16(const u16* g, u16* l) {
    __builtin_amdgcn_global_load_lds(
        (const __attribute__((address_space(1))) unsigned int*)g,
        (__attribute__((address_space(3))) unsigned int*)l, 16, 0, 0);
}
// pack 4 fp32 -> 4 bf16 (truncation; bias cancels in O/L ratio)
__device__ __forceinline__ short4v pack4(float a, float b, float c, float d) {
    union { float f; unsigned int u; } xa, xb, xc, xd;
    xa.f = a; xb.f = b; xc.f = c; xd.f = d;
    union { unsigned int u2[2]; short4v s; } r;
    r.u2[0] = (xa.u >> 16) | (xb.u & 0xffff0000u);
    r.u2[1] = (xc.u >> 16) | (xd.u & 0xffff0000u);
    return r.s;
}

// ---------------------------------------------------------------------------
// Fused setup: [0,4096) cast x->bf16; [4096,7168) transpose Wqkv;
// [7168,8192) transpose Wout; [8192,8704) rope table.
// ---------------------------------------------------------------------------
__global__ __launch_bounds__(256) void setup_kernel(
    const float* __restrict__ x, const float* __restrict__ Wqkv,
    const float* __restrict__ Wout, u16* __restrict__ xb,
    u16* __restrict__ WqkvT, u16* __restrict__ WoutT,
    float* __restrict__ costab, float* __restrict__ sintab)
{
    const int bid = blockIdx.x;
    const int tid = threadIdx.x;

    if (bid < 4096) {
        int i = (bid * 256 + tid) * 4;
        float4 v = *(const float4*)(x + i);
        ushort4 w;
        w.x = f2b(v.x); w.y = f2b(v.y); w.z = f2b(v.z); w.w = f2b(v.w);
        *(ushort4*)(xb + i) = w;
        return;
    }
    if (bid < 8192) {
        const float* in; u16* out; int R, Cn, bx, by;
        if (bid < 7168) { in = Wqkv; out = WqkvT; R = 1024; Cn = 3072;
                          int id = bid - 4096; bx = id % 96; by = id / 96; }
        else            { in = Wout; out = WoutT; R = 1024; Cn = 1024;
                          int id = bid - 7168; bx = id & 31; by = id >> 5; }
        __shared__ u16 tile[32][33];
        const int tx = tid & 31, ty = tid >> 5;
        const int r0 = by * 32, c0 = bx * 32;
#pragma unroll
        for (int rr = ty; rr < 32; rr += 8)
            tile[tx][rr] = f2b(in[(size_t)(r0 + rr) * Cn + c0 + tx]);
        __syncthreads();
#pragma unroll
        for (int rr = ty; rr < 32; rr += 8)
            out[(size_t)(c0 + rr) * R + r0 + tx] = tile[rr][tx];
        return;
    }
    {
        int idx = (bid - 8192) * 256 + tid;
        int t = idx >> 6, d = idx & 63;
        const float nl32 = -0.28782313662425576f;   // -ln(10000)/32
        float f = __expf((float)(d & 31) * nl32);
        float s, c;
        __sincosf((float)t * f, &s, &c);
        costab[idx] = c; sintab[idx] = s;
    }
}

// ---------------------------------------------------------------------------
// MFMA GEMM (unchanged): C[M,N] = A @ Bt^T (+bias). OBF: bf16/fp32 out.
// ---------------------------------------------------------------------------
template<int OBF>
__global__ __launch_bounds__(256) void gemm_bt_mfma(
    const u16* __restrict__ A, const u16* __restrict__ Bt,
    void* __restrict__ Cv, const float* __restrict__ bias,
    int M, int N, int K)
{
    __shared__ u16 As[128 * 32];
    __shared__ u16 Bs[128 * 32];

    const int tid = threadIdx.x;
    const int wave = tid >> 6, lane = tid & 63;
    const int col = lane & 15, quad = lane >> 4;
    const int wm = (wave & 1) * 64, wn = (wave >> 1) * 64;
    const int m0 = blockIdx.y * 128, n0 = blockIdx.x * 128;

    f32x4 acc[4][4];
#pragma unroll
    for (int i = 0; i < 4; ++i)
#pragma unroll
        for (int j = 0; j < 4; ++j) acc[i][j] = f32x4{0.f, 0.f, 0.f, 0.f};

    const int c1 = tid, c2 = tid + 256;
    const u16* a1 = A + (size_t)(m0 + (c1 >> 2)) * K + (c1 & 3) * 8;
    const u16* a2 = A + (size_t)(m0 + (c2 >> 2)) * K + (c2 & 3) * 8;
    const u16* b1 = Bt + (size_t)(n0 + (c1 >> 2)) * K + (c1 & 3) * 8;
    const u16* b2 = Bt + (size_t)(n0 + (c2 >> 2)) * K + (c2 & 3) * 8;
    u16* la1 = As + c1 * 8; u16* la2 = As + c2 * 8;
    u16* lb1 = Bs + c1 * 8; u16* lb2 = Bs + c2 * 8;

    for (int k0 = 0; k0 < K; k0 += 32) {
        __syncthreads();
        gl_lds16(a1 + k0, la1);
        gl_lds16(a2 + k0, la2);
        gl_lds16(b1 + k0, lb1);
        gl_lds16(b2 + k0, lb2);
        __syncthreads();

        short8 af[4], bfr[4];
#pragma unroll
        for (int i = 0; i < 4; ++i) {
            af[i]  = *(const short8*)&As[(wm + i * 16 + col) * 32 + quad * 8];
            bfr[i] = *(const short8*)&Bs[(wn + i * 16 + col) * 32 + quad * 8];
        }
#pragma unroll
        for (int i = 0; i < 4; ++i)
#pragma unroll
            for (int j = 0; j < 4; ++j)
                acc[i][j] = __builtin_amdgcn_mfma_f32_16x16x32_bf16(
                    af[i], bfr[j], acc[i][j], 0, 0, 0);
    }

#pragma unroll
    for (int j = 0; j < 4; ++j) {
        int n = n0 + wn + j * 16 + col;
        float bv = bias ? bias[n] : 0.f;
#pragma unroll
        for (int i = 0; i < 4; ++i) {
            int mbase = m0 + wm + i * 16 + quad * 4;
#pragma unroll
            for (int r = 0; r < 4; ++r) {
                if (OBF) ((u16*)Cv)[(size_t)(mbase + r) * N + n] = f2b(acc[i][j][r] + bv);
                else     ((float*)Cv)[(size_t)(mbase + r) * N + n] = acc[i][j][r] + bv;
            }
        }
    }
}

// ---------------------------------------------------------------------------
// Prep: qkvb bf16 -> rope(q)*0.125, rope(k) head-major Qb/Kb[bh][t][64];
// V written as attn LDS-image: Vimg[bh][kt][slot t=0..255][8 u16], where
// slot t = {dt=t>>7, g=(t>>5)&3, hi=(t&31)>>4, dpair=t&15}: bytes0-7 =
// V[d=dt*32+2dpair][keys kt*32+g*8+hi*4..+3], bytes8-15 = same keys, d+1.
// Attn then DMAs the 4KB tile lane-linearly and reads it conflict-free.
// ---------------------------------------------------------------------------
__global__ __launch_bounds__(256) void prep_kernel(
    const u16* __restrict__ qkvb, const float* __restrict__ costab,
    const float* __restrict__ sintab, u16* __restrict__ Qb,
    u16* __restrict__ Kb, u16* __restrict__ Vimg)
{
    __shared__ u16 Vls[64][72];

    const int tid = threadIdx.x;
    const int bh = blockIdx.y;
    const int t0 = blockIdx.x * 64;
    const int b = bh >> 4, h = bh & 15;
    const int t_loc = tid >> 2;
    const int d0 = (tid & 3) * 16;

    const int t = t0 + t_loc;
    const u16* qp = qkvb + ((size_t)(b * T_SEQ + t)) * 3072 + h * 64 + d0;

    float ct[16], st[16];
    {
        const float* cp = costab + (size_t)t * 64 + d0;
        const float* sp = sintab + (size_t)t * 64 + d0;
#pragma unroll
        for (int j = 0; j < 16; j += 4) {
            *(float4*)&ct[j] = *(const float4*)(cp + j);
            *(float4*)&st[j] = *(const float4*)(sp + j);
        }
    }

#pragma unroll
    for (int part = 0; part < 2; ++part) {
        const float sc = part ? 1.f : 0.125f;   // fold QK^T scale into Q
        const u16* src = qp + part * 1024;
        u16* dst = (part ? Kb : Qb) + ((size_t)(bh * T_SEQ + t)) * 64 + d0;
        short8 v0 = *(const short8*)(src);
        short8 v1 = *(const short8*)(src + 8);
        float f[16];
#pragma unroll
        for (int j = 0; j < 8; ++j) { f[j] = b2f((u16)v0[j]); f[8 + j] = b2f((u16)v1[j]); }
        u16 o[16];
#pragma unroll
        for (int i = 0; i < 8; ++i) {
            float e = f[2 * i], od = f[2 * i + 1];
            o[2 * i]     = f2b((e * ct[2 * i]      - od * st[2 * i]) * sc);
            o[2 * i + 1] = f2b((od * ct[2 * i + 1] + e  * st[2 * i + 1]) * sc);
        }
        *(short8*)(dst)     = *(short8*)&o[0];
        *(short8*)(dst + 8) = *(short8*)&o[8];
    }

    {
        const u16* src = qp + 2048;
        *(short8*)&Vls[t_loc][d0]     = *(const short8*)(src);
        *(short8*)&Vls[t_loc][d0 + 8] = *(const short8*)(src + 8);
    }
    __syncthreads();
    {
        const int dt    = tid >> 7;
        const int g     = (tid >> 5) & 3;
        const int hi2   = (tid >> 4) & 1;
        const int dpair = tid & 15;
        const int kl0 = g * 8 + hi2 * 4;
        const int d0v = dt * 32 + 2 * dpair;
        const int kt_base = blockIdx.x * 2;   // two 32-key tiles per block
#pragma unroll
        for (int ktl = 0; ktl < 2; ++ktl) {
            u16 o[8];
#pragma unroll
            for (int j = 0; j < 4; ++j) {
                o[j]     = Vls[ktl * 32 + kl0 + j][d0v];
                o[4 + j] = Vls[ktl * 32 + kl0 + j][d0v + 1];
            }
            u16* dst = Vimg + ((size_t)(bh * 64 + kt_base + ktl)) * 2048 + tid * 8;
            *(short8*)dst = *(short8*)&o[0];
        }
    }
}

// ---------------------------------------------------------------------------
// MFMA flash attention, S^T formulation, double-buffered LDS.
// Wave = 32 q-rows; block = 4 waves = 128 rows; K-split segs=2; grid 1024.
// Loop: barrier (drains prev DMA) -> prefetch next tile into other buffer
// -> compute on current buffer. DMA overlaps the full compute phase.
// V reads lane-linear b64 (conflict-free via Vimg); K reads lane-linear b128.
// ---------------------------------------------------------------------------
__global__ __launch_bounds__(256) void attn32_kernel(
    const u16* __restrict__ Qb, const u16* __restrict__ Kb,
    const u16* __restrict__ Vimg, float* __restrict__ po, float* __restrict__ pl)
{
    __shared__ u16 Kbuf[2][2048];   // 4 KB per buffer
    __shared__ u16 Vbuf[2][2048];

    const int tid = threadIdx.x;
    const int wave = tid >> 6, lane = tid & 63;
    const int qcol = lane & 31;
    const int hi = lane >> 5;

    const int bid = blockIdx.x;
    const int bh = bid >> 5;
    const int seg = (bid >> 4) & 1;
    const int qblk = bid & 15;
    const int qrow0 = qblk * 128 + wave * 32;

    // Q B-frags (32x32x16): lane(n=q, hi): Q[q][c*16 + hi*8 + j]
    short8 qa[4];
    {
        const u16* qp = Qb + ((size_t)(bh * T_SEQ + qrow0 + qcol)) * 64 + hi * 8;
#pragma unroll
        for (int c = 0; c < 4; ++c) qa[c] = *(const short8*)(qp + c * 16);
    }

    short4v ones4;
#pragma unroll
    for (int j = 0; j < 4; ++j) ones4[j] = (short)0x3F80;

    f32x16 O0, O1, L;
#pragma unroll
    for (int i = 0; i < 16; ++i) { O0[i] = 0.f; O1[i] = 0.f; L[i] = 0.f; }

    // staging sources (16B per thread per tile, each)
    const u16* kg_ptr = Kb + ((size_t)bh * T_SEQ + qcol) * 64 + wave * 16 + hi * 8;
    const u16* vg_ptr = Vimg + ((size_t)bh * 64) * 2048 + tid * 8;

    const int kt0 = seg * 32;
    // prologue: stage first tile into buffer 0
    gl_lds16(kg_ptr + (size_t)kt0 * 2048, &Kbuf[0][tid * 8]);
    gl_lds16(vg_ptr + (size_t)kt0 * 2048, &Vbuf[0][tid * 8]);

    for (int i = 0; i < 32; ++i) {
        const int buf = i & 1;
        __syncthreads();                        // drains DMA for `buf`
        if (i < 31) {                           // prefetch next into other buf
            gl_lds16(kg_ptr + (size_t)(kt0 + i + 1) * 2048, &Kbuf[buf ^ 1][tid * 8]);
            gl_lds16(vg_ptr + (size_t)(kt0 + i + 1) * 2048, &Vbuf[buf ^ 1][tid * 8]);
        }

        short8 kf[4];
#pragma unroll
        for (int f = 0; f < 4; ++f)
            kf[f] = *(const short8*)&Kbuf[buf][(f * 64 + lane) * 8];

        // S^T = K * Q^T
        f32x16 sT;
#pragma unroll
        for (int ii = 0; ii < 16; ++ii) sT[ii] = 0.f;
#pragma unroll
        for (int c = 0; c < 4; ++c)
            sT = __builtin_amdgcn_mfma_f32_32x32x16_bf16(kf[c], qa[c], sT, 0, 0, 0);

        // p = exp(s); pack reg groups into 32x32x8 B-frags in registers
        short4v pb[4];
#pragma unroll
        for (int g = 0; g < 4; ++g)
            pb[g] = pack4(__expf(sT[4 * g + 0]), __expf(sT[4 * g + 1]),
                          __expf(sT[4 * g + 2]), __expf(sT[4 * g + 3]));

        // O^T += V^T * P^T ; L += 1 * P^T   (V reads lane-linear)
#pragma unroll
        for (int g = 0; g < 4; ++g) {
            short4v va0 = *(const short4v*)&Vbuf[buf][g * 256 + lane * 4];
            short4v va1 = *(const short4v*)&Vbuf[buf][1024 + g * 256 + lane * 4];
            O0 = __builtin_amdgcn_mfma_f32_32x32x8bf16_1k(va0, pb[g], O0, 0, 0, 0);
            O1 = __builtin_amdgcn_mfma_f32_32x32x8bf16_1k(va1, pb[g], O1, 0, 0, 0);
            L  = __builtin_amdgcn_mfma_f32_32x32x8bf16_1k(ones4, pb[g], L, 0, 0, 0);
        }
    }

    // epilogue: C col=q, row d_local=(r&3)+8*(r>>2)+4*hi; store fp32 partials
    const size_t prow = ((size_t)(seg * 32 + bh)) * T_SEQ + qrow0 + qcol;
    float* op = po + prow * 64;
#pragma unroll
    for (int g2 = 0; g2 < 4; ++g2) {
        int dd = g2 * 8 + hi * 4;
        *(float4*)(op + dd)      = make_float4(O0[4 * g2 + 0], O0[4 * g2 + 1],
                                               O0[4 * g2 + 2], O0[4 * g2 + 3]);
        *(float4*)(op + 32 + dd) = make_float4(O1[4 * g2 + 0], O1[4 * g2 + 1],
                                               O1[4 * g2 + 2], O1[4 * g2 + 3]);
    }
    if (hi == 0) pl[prow] = L[0];
}

// ---------------------------------------------------------------------------
// Combine: out = (O_s0 + O_s1) / (L_s0 + L_s1), write bf16 head-merged aob.
// ---------------------------------------------------------------------------
__global__ __launch_bounds__(256) void attn_combine_kernel(
    const float* __restrict__ po, const float* __restrict__ pl,
    u16* __restrict__ aob)
{
    const int idx = blockIdx.x * 256 + (int)threadIdx.x;
    const int row = idx >> 4;        // bh*2048 + t
    const int d4 = idx & 15;

    float4 o0 = *(const float4*)(po + (size_t)row * 64 + d4 * 4);
    float4 o1 = *(const float4*)(po + ((size_t)row + 65536) * 64 + d4 * 4);
    float L = pl[row] + pl[row + 65536];
    float inv = 1.f / L;

    const int bh = row >> 11, t = row & 2047;
    const int b = bh >> 4, h = bh & 15;
    ushort4 w;
    w.x = f2b((o0.x + o1.x) * inv);
    w.y = f2b((o0.y + o1.y) * inv);
    w.z = f2b((o0.z + o1.z) * inv);
    w.w = f2b((o0.w + o1.w) * inv);
    *(ushort4*)(aob + ((size_t)(b * T_SEQ + t)) * 1024 + h * 64 + d4 * 4) = w;
}

// ---------------------------------------------------------------------------
extern "C" void kernel_launch(void* const* d_in, const int* in_sizes, int n_in,
                              void* d_out, int out_size, void* d_ws, size_t ws_size,
                              hipStream_t stream)
{
    const float* x    = (const float*)d_in[0];
    const float* Wqkv = (const float*)d_in[1];
    const float* Wout = (const float*)d_in[2];
    const float* bout = (const float*)d_in[3];
    float* out = (float*)d_out;

    char* w = (char*)d_ws;
    u16* qkvb    = (u16*)(w);                   // 25,165,824  (dead after prep)
    u16* xb      = (u16*)(w + 25165824);        //  8,388,608  (dead after gemm1)
    u16* WqkvT   = (u16*)(w + 33554432);        //  6,291,456  (dead after gemm1)
    u16* WoutT   = (u16*)(w + 39845888);        //  2,097,152
    u16* aob     = (u16*)(w + 41943040);        //  8,388,608
    u16* Qb      = (u16*)(w + 50331648);        //  8,388,608
    u16* Kb      = (u16*)(w + 58720256);        //  8,388,608
    u16* Vimg    = (u16*)(w + 67108864);        //  8,388,608
    float* ctab  = (float*)(w + 75497472);      //    524,288
    float* stab  = (float*)(w + 76021760);      //    524,288
    // attn partials alias dead buffers (proven safe R8/R9):
    float* po    = (float*)(w);                 // 33,554,432 over qkvb+xb
    float* pl    = (float*)(w + 33554432);      //    524,288 over WqkvT

    dim3 blk(256);
    setup_kernel<<<dim3(8704), blk, 0, stream>>>(x, Wqkv, Wout, xb, WqkvT, WoutT, ctab, stab);
    gemm_bt_mfma<1><<<dim3(24, 32), blk, 0, stream>>>(xb, WqkvT, qkvb, nullptr, 4096, 3072, 1024);
    prep_kernel<<<dim3(32, 32), blk, 0, stream>>>(qkvb, ctab, stab, Qb, Kb, Vimg);
    attn32_kernel<<<dim3(1024), blk, 0, stream>>>(Qb, Kb, Vimg, po, pl);
    attn_combine_kernel<<<dim3(4096), blk, 0, stream>>>(po, pl, aob);
    gemm_bt_mfma<0><<<dim3(8, 32), blk, 0, stream>>>(aob, WoutT, out, bout, 4096, 1024, 1024);
}

// Round 11
// 223.437 us; speedup vs baseline: 1.0619x; 1.0619x over previous
//
#include <hip/hip_runtime.h>
#include <math.h>

// B=2, T=2048, DIM=1024, H=16, HD=64. Inputs fp32, output fp32.
// R10 post-mortem: Vimg killed all bank conflicts (4.2e6 -> 0) but explicit
// dbuf regressed (compiler drains fresh DMA before compute anyway). R11:
// revert to R9's 2-barrier loop, keep Vimg, stage 64 keys/round (half the
// barriers), fold 0.125*log2e into Q so softmax = raw v_exp_f32 (2^x).

typedef unsigned short u16;
typedef __attribute__((ext_vector_type(8))) short short8;
typedef __attribute__((ext_vector_type(4))) short short4v;
typedef __attribute__((ext_vector_type(4))) float f32x4;
typedef __attribute__((ext_vector_type(16))) float f32x16;

#define T_SEQ 2048

#if __has_builtin(__builtin_amdgcn_exp2f)
#define EXP2(x) __builtin_amdgcn_exp2f(x)
#else
#define EXP2(x) exp2f(x)
#endif

__device__ __forceinline__ float b2f(u16 u) {
    union { unsigned int i; float f; } x; x.i = ((unsigned int)u) << 16; return x.f;
}
__device__ __forceinline__ u16 f2b(float f) {
    union { float f; unsigned int i; } x; x.f = f;
    return (u16)((x.i + 0x7FFFu + ((x.i >> 16) & 1u)) >> 16);  // RNE
}
__device__ __forceinline__ void gl_lds16(const u16* g, u16* l) {
    __builtin_amdgcn_global_load_lds(
        (const __attribute__((address_space(1))) unsigned int*)g,
        (__attribute__((address_space(3))) unsigned int*)l, 16, 0, 0);
}
// pack 4 fp32 -> 4 bf16 (truncation; bias cancels in O/L ratio)
__device__ __forceinline__ short4v pack4(float a, float b, float c, float d) {
    union { float f; unsigned int u; } xa, xb, xc, xd;
    xa.f = a; xb.f = b; xc.f = c; xd.f = d;
    union { unsigned int u2[2]; short4v s; } r;
    r.u2[0] = (xa.u >> 16) | (xb.u & 0xffff0000u);
    r.u2[1] = (xc.u >> 16) | (xd.u & 0xffff0000u);
    return r.s;
}

// ---------------------------------------------------------------------------
// Fused setup: [0,4096) cast x->bf16; [4096,7168) transpose Wqkv;
// [7168,8192) transpose Wout; [8192,8704) rope table.
// ---------------------------------------------------------------------------
__global__ __launch_bounds__(256) void setup_kernel(
    const float* __restrict__ x, const float* __restrict__ Wqkv,
    const float* __restrict__ Wout, u16* __restrict__ xb,
    u16* __restrict__ WqkvT, u16* __restrict__ WoutT,
    float* __restrict__ costab, float* __restrict__ sintab)
{
    const int bid = blockIdx.x;
    const int tid = threadIdx.x;

    if (bid < 4096) {
        int i = (bid * 256 + tid) * 4;
        float4 v = *(const float4*)(x + i);
        ushort4 w;
        w.x = f2b(v.x); w.y = f2b(v.y); w.z = f2b(v.z); w.w = f2b(v.w);
        *(ushort4*)(xb + i) = w;
        return;
    }
    if (bid < 8192) {
        const float* in; u16* out; int R, Cn, bx, by;
        if (bid < 7168) { in = Wqkv; out = WqkvT; R = 1024; Cn = 3072;
                          int id = bid - 4096; bx = id % 96; by = id / 96; }
        else            { in = Wout; out = WoutT; R = 1024; Cn = 1024;
                          int id = bid - 7168; bx = id & 31; by = id >> 5; }
        __shared__ u16 tile[32][33];
        const int tx = tid & 31, ty = tid >> 5;
        const int r0 = by * 32, c0 = bx * 32;
#pragma unroll
        for (int rr = ty; rr < 32; rr += 8)
            tile[tx][rr] = f2b(in[(size_t)(r0 + rr) * Cn + c0 + tx]);
        __syncthreads();
#pragma unroll
        for (int rr = ty; rr < 32; rr += 8)
            out[(size_t)(c0 + rr) * R + r0 + tx] = tile[rr][tx];
        return;
    }
    {
        int idx = (bid - 8192) * 256 + tid;
        int t = idx >> 6, d = idx & 63;
        const float nl32 = -0.28782313662425576f;   // -ln(10000)/32
        float f = __expf((float)(d & 31) * nl32);
        float s, c;
        __sincosf((float)t * f, &s, &c);
        costab[idx] = c; sintab[idx] = s;
    }
}

// ---------------------------------------------------------------------------
// MFMA GEMM (unchanged): C[M,N] = A @ Bt^T (+bias). OBF: bf16/fp32 out.
// ---------------------------------------------------------------------------
template<int OBF>
__global__ __launch_bounds__(256) void gemm_bt_mfma(
    const u16* __restrict__ A, const u16* __restrict__ Bt,
    void* __restrict__ Cv, const float* __restrict__ bias,
    int M, int N, int K)
{
    __shared__ u16 As[128 * 32];
    __shared__ u16 Bs[128 * 32];

    const int tid = threadIdx.x;
    const int wave = tid >> 6, lane = tid & 63;
    const int col = lane & 15, quad = lane >> 4;
    const int wm = (wave & 1) * 64, wn = (wave >> 1) * 64;
    const int m0 = blockIdx.y * 128, n0 = blockIdx.x * 128;

    f32x4 acc[4][4];
#pragma unroll
    for (int i = 0; i < 4; ++i)
#pragma unroll
        for (int j = 0; j < 4; ++j) acc[i][j] = f32x4{0.f, 0.f, 0.f, 0.f};

    const int c1 = tid, c2 = tid + 256;
    const u16* a1 = A + (size_t)(m0 + (c1 >> 2)) * K + (c1 & 3) * 8;
    const u16* a2 = A + (size_t)(m0 + (c2 >> 2)) * K + (c2 & 3) * 8;
    const u16* b1 = Bt + (size_t)(n0 + (c1 >> 2)) * K + (c1 & 3) * 8;
    const u16* b2 = Bt + (size_t)(n0 + (c2 >> 2)) * K + (c2 & 3) * 8;
    u16* la1 = As + c1 * 8; u16* la2 = As + c2 * 8;
    u16* lb1 = Bs + c1 * 8; u16* lb2 = Bs + c2 * 8;

    for (int k0 = 0; k0 < K; k0 += 32) {
        __syncthreads();
        gl_lds16(a1 + k0, la1);
        gl_lds16(a2 + k0, la2);
        gl_lds16(b1 + k0, lb1);
        gl_lds16(b2 + k0, lb2);
        __syncthreads();

        short8 af[4], bfr[4];
#pragma unroll
        for (int i = 0; i < 4; ++i) {
            af[i]  = *(const short8*)&As[(wm + i * 16 + col) * 32 + quad * 8];
            bfr[i] = *(const short8*)&Bs[(wn + i * 16 + col) * 32 + quad * 8];
        }
#pragma unroll
        for (int i = 0; i < 4; ++i)
#pragma unroll
            for (int j = 0; j < 4; ++j)
                acc[i][j] = __builtin_amdgcn_mfma_f32_16x16x32_bf16(
                    af[i], bfr[j], acc[i][j], 0, 0, 0);
    }

#pragma unroll
    for (int j = 0; j < 4; ++j) {
        int n = n0 + wn + j * 16 + col;
        float bv = bias ? bias[n] : 0.f;
#pragma unroll
        for (int i = 0; i < 4; ++i) {
            int mbase = m0 + wm + i * 16 + quad * 4;
#pragma unroll
            for (int r = 0; r < 4; ++r) {
                if (OBF) ((u16*)Cv)[(size_t)(mbase + r) * N + n] = f2b(acc[i][j][r] + bv);
                else     ((float*)Cv)[(size_t)(mbase + r) * N + n] = acc[i][j][r] + bv;
            }
        }
    }
}

// ---------------------------------------------------------------------------
// Prep: qkvb bf16 -> rope(q)*0.125*log2e, rope(k) head-major Qb/Kb[bh][t][64];
// V written as attn LDS-image Vimg[bh][kt][slot 0..255][8 u16] (R10-verified).
// ---------------------------------------------------------------------------
__global__ __launch_bounds__(256) void prep_kernel(
    const u16* __restrict__ qkvb, const float* __restrict__ costab,
    const float* __restrict__ sintab, u16* __restrict__ Qb,
    u16* __restrict__ Kb, u16* __restrict__ Vimg)
{
    __shared__ u16 Vls[64][72];

    const int tid = threadIdx.x;
    const int bh = blockIdx.y;
    const int t0 = blockIdx.x * 64;
    const int b = bh >> 4, h = bh & 15;
    const int t_loc = tid >> 2;
    const int d0 = (tid & 3) * 16;

    const int t = t0 + t_loc;
    const u16* qp = qkvb + ((size_t)(b * T_SEQ + t)) * 3072 + h * 64 + d0;

    float ct[16], st[16];
    {
        const float* cp = costab + (size_t)t * 64 + d0;
        const float* sp = sintab + (size_t)t * 64 + d0;
#pragma unroll
        for (int j = 0; j < 16; j += 4) {
            *(float4*)&ct[j] = *(const float4*)(cp + j);
            *(float4*)&st[j] = *(const float4*)(sp + j);
        }
    }

#pragma unroll
    for (int part = 0; part < 2; ++part) {
        // fold QK^T scale AND log2(e) into Q: p = 2^(s_scaled) in attn.
        const float sc = part ? 1.f : 0.18033688011112042f;  // 0.125*log2(e)
        const u16* src = qp + part * 1024;
        u16* dst = (part ? Kb : Qb) + ((size_t)(bh * T_SEQ + t)) * 64 + d0;
        short8 v0 = *(const short8*)(src);
        short8 v1 = *(const short8*)(src + 8);
        float f[16];
#pragma unroll
        for (int j = 0; j < 8; ++j) { f[j] = b2f((u16)v0[j]); f[8 + j] = b2f((u16)v1[j]); }
        u16 o[16];
#pragma unroll
        for (int i = 0; i < 8; ++i) {
            float e = f[2 * i], od = f[2 * i + 1];
            o[2 * i]     = f2b((e * ct[2 * i]      - od * st[2 * i]) * sc);
            o[2 * i + 1] = f2b((od * ct[2 * i + 1] + e  * st[2 * i + 1]) * sc);
        }
        *(short8*)(dst)     = *(short8*)&o[0];
        *(short8*)(dst + 8) = *(short8*)&o[8];
    }

    {
        const u16* src = qp + 2048;
        *(short8*)&Vls[t_loc][d0]     = *(const short8*)(src);
        *(short8*)&Vls[t_loc][d0 + 8] = *(const short8*)(src + 8);
    }
    __syncthreads();
    {
        const int dt    = tid >> 7;
        const int g     = (tid >> 5) & 3;
        const int hi2   = (tid >> 4) & 1;
        const int dpair = tid & 15;
        const int kl0 = g * 8 + hi2 * 4;
        const int d0v = dt * 32 + 2 * dpair;
        const int kt_base = blockIdx.x * 2;   // two 32-key tiles per block
#pragma unroll
        for (int ktl = 0; ktl < 2; ++ktl) {
            u16 o[8];
#pragma unroll
            for (int j = 0; j < 4; ++j) {
                o[j]     = Vls[ktl * 32 + kl0 + j][d0v];
                o[4 + j] = Vls[ktl * 32 + kl0 + j][d0v + 1];
            }
            u16* dst = Vimg + ((size_t)(bh * 64 + kt_base + ktl)) * 2048 + tid * 8;
            *(short8*)dst = *(short8*)&o[0];
        }
    }
}

// ---------------------------------------------------------------------------
// MFMA flash attention, S^T formulation, 2-barrier rounds of 64 keys.
// Wave = 32 q-rows; block = 4 waves; K-split segs=2; grid 1024.
// Round: barrier; 4 DMAs (2 K-tiles + 2 V-tiles); barrier; compute 2 halves.
// V reads lane-linear b64 (conflict-free via Vimg); K reads lane-linear b128.
// p = 2^s via raw v_exp_f32 (scale+log2e folded into Q).
// ---------------------------------------------------------------------------
__global__ __launch_bounds__(256) void attn32_kernel(
    const u16* __restrict__ Qb, const u16* __restrict__ Kb,
    const u16* __restrict__ Vimg, float* __restrict__ po, float* __restrict__ pl)
{
    __shared__ u16 Kbuf[2][2048];   // 4 KB per 32-key tile
    __shared__ u16 Vbuf[2][2048];

    const int tid = threadIdx.x;
    const int wave = tid >> 6, lane = tid & 63;
    const int qcol = lane & 31;
    const int hi = lane >> 5;

    const int bid = blockIdx.x;
    const int bh = bid >> 5;
    const int seg = (bid >> 4) & 1;
    const int qblk = bid & 15;
    const int qrow0 = qblk * 128 + wave * 32;

    // Q B-frags (32x32x16): lane(n=q, hi): Q[q][c*16 + hi*8 + j]
    short8 qa[4];
    {
        const u16* qp = Qb + ((size_t)(bh * T_SEQ + qrow0 + qcol)) * 64 + hi * 8;
#pragma unroll
        for (int c = 0; c < 4; ++c) qa[c] = *(const short8*)(qp + c * 16);
    }

    short4v ones4;
#pragma unroll
    for (int j = 0; j < 4; ++j) ones4[j] = (short)0x3F80;

    f32x16 O0, O1, L;
#pragma unroll
    for (int i = 0; i < 16; ++i) { O0[i] = 0.f; O1[i] = 0.f; L[i] = 0.f; }

    const u16* kg_ptr = Kb + ((size_t)bh * T_SEQ + qcol) * 64 + wave * 16 + hi * 8;
    const u16* vg_ptr = Vimg + ((size_t)bh * 64) * 2048 + tid * 8;

    const int kt0 = seg * 32;
    for (int r = 0; r < 16; ++r) {
        const int kt = kt0 + r * 2;
        __syncthreads();
        gl_lds16(kg_ptr + (size_t)kt * 2048,       &Kbuf[0][tid * 8]);
        gl_lds16(kg_ptr + (size_t)(kt + 1) * 2048, &Kbuf[1][tid * 8]);
        gl_lds16(vg_ptr + (size_t)kt * 2048,       &Vbuf[0][tid * 8]);
        gl_lds16(vg_ptr + (size_t)(kt + 1) * 2048, &Vbuf[1][tid * 8]);
        __syncthreads();

#pragma unroll
        for (int half = 0; half < 2; ++half) {
            short8 kf[4];
#pragma unroll
            for (int f = 0; f < 4; ++f)
                kf[f] = *(const short8*)&Kbuf[half][(f * 64 + lane) * 8];

            // S^T = K * Q^T (scale/log2e pre-folded into Q)
            f32x16 sT;
#pragma unroll
            for (int ii = 0; ii < 16; ++ii) sT[ii] = 0.f;
#pragma unroll
            for (int c = 0; c < 4; ++c)
                sT = __builtin_amdgcn_mfma_f32_32x32x16_bf16(kf[c], qa[c], sT, 0, 0, 0);

            // p = 2^s; pack into 32x32x8 B-frags in registers
            short4v pb[4];
#pragma unroll
            for (int g = 0; g < 4; ++g)
                pb[g] = pack4(EXP2(sT[4 * g + 0]), EXP2(sT[4 * g + 1]),
                              EXP2(sT[4 * g + 2]), EXP2(sT[4 * g + 3]));

            // O^T += V^T * P^T ; L += 1 * P^T  (V reads lane-linear)
#pragma unroll
            for (int g = 0; g < 4; ++g) {
                short4v va0 = *(const short4v*)&Vbuf[half][g * 256 + lane * 4];
                short4v va1 = *(const short4v*)&Vbuf[half][1024 + g * 256 + lane * 4];
                O0 = __builtin_amdgcn_mfma_f32_32x32x8bf16_1k(va0, pb[g], O0, 0, 0, 0);
                O1 = __builtin_amdgcn_mfma_f32_32x32x8bf16_1k(va1, pb[g], O1, 0, 0, 0);
                L  = __builtin_amdgcn_mfma_f32_32x32x8bf16_1k(ones4, pb[g], L, 0, 0, 0);
            }
        }
    }

    // epilogue: C col=q, row d_local=(r&3)+8*(r>>2)+4*hi; store fp32 partials
    const size_t prow = ((size_t)(seg * 32 + bh)) * T_SEQ + qrow0 + qcol;
    float* op = po + prow * 64;
#pragma unroll
    for (int g2 = 0; g2 < 4; ++g2) {
        int dd = g2 * 8 + hi * 4;
        *(float4*)(op + dd)      = make_float4(O0[4 * g2 + 0], O0[4 * g2 + 1],
                                               O0[4 * g2 + 2], O0[4 * g2 + 3]);
        *(float4*)(op + 32 + dd) = make_float4(O1[4 * g2 + 0], O1[4 * g2 + 1],
                                               O1[4 * g2 + 2], O1[4 * g2 + 3]);
    }
    if (hi == 0) pl[prow] = L[0];
}

// ---------------------------------------------------------------------------
// Combine: out = (O_s0 + O_s1) / (L_s0 + L_s1), write bf16 head-merged aob.
// ---------------------------------------------------------------------------
__global__ __launch_bounds__(256) void attn_combine_kernel(
    const float* __restrict__ po, const float* __restrict__ pl,
    u16* __restrict__ aob)
{
    const int idx = blockIdx.x * 256 + (int)threadIdx.x;
    const int row = idx >> 4;        // bh*2048 + t
    const int d4 = idx & 15;

    float4 o0 = *(const float4*)(po + (size_t)row * 64 + d4 * 4);
    float4 o1 = *(const float4*)(po + ((size_t)row + 65536) * 64 + d4 * 4);
    float L = pl[row] + pl[row + 65536];
    float inv = 1.f / L;

    const int bh = row >> 11, t = row & 2047;
    const int b = bh >> 4, h = bh & 15;
    ushort4 w;
    w.x = f2b((o0.x + o1.x) * inv);
    w.y = f2b((o0.y + o1.y) * inv);
    w.z = f2b((o0.z + o1.z) * inv);
    w.w = f2b((o0.w + o1.w) * inv);
    *(ushort4*)(aob + ((size_t)(b * T_SEQ + t)) * 1024 + h * 64 + d4 * 4) = w;
}

// ---------------------------------------------------------------------------
extern "C" void kernel_launch(void* const* d_in, const int* in_sizes, int n_in,
                              void* d_out, int out_size, void* d_ws, size_t ws_size,
                              hipStream_t stream)
{
    const float* x    = (const float*)d_in[0];
    const float* Wqkv = (const float*)d_in[1];
    const float* Wout = (const float*)d_in[2];
    const float* bout = (const float*)d_in[3];
    float* out = (float*)d_out;

    char* w = (char*)d_ws;
    u16* qkvb    = (u16*)(w);                   // 25,165,824  (dead after prep)
    u16* xb      = (u16*)(w + 25165824);        //  8,388,608  (dead after gemm1)
    u16* WqkvT   = (u16*)(w + 33554432);        //  6,291,456  (dead after gemm1)
    u16* WoutT   = (u16*)(w + 39845888);        //  2,097,152
    u16* aob     = (u16*)(w + 41943040);        //  8,388,608
    u16* Qb      = (u16*)(w + 50331648);        //  8,388,608
    u16* Kb      = (u16*)(w + 58720256);        //  8,388,608
    u16* Vimg    = (u16*)(w + 67108864);        //  8,388,608
    float* ctab  = (float*)(w + 75497472);      //    524,288
    float* stab  = (float*)(w + 76021760);      //    524,288
    // attn partials alias dead buffers (proven safe R8-R10):
    float* po    = (float*)(w);                 // 33,554,432 over qkvb+xb
    float* pl    = (float*)(w + 33554432);      //    524,288 over WqkvT

    dim3 blk(256);
    setup_kernel<<<dim3(8704), blk, 0, stream>>>(x, Wqkv, Wout, xb, WqkvT, WoutT, ctab, stab);
    gemm_bt_mfma<1><<<dim3(24, 32), blk, 0, stream>>>(xb, WqkvT, qkvb, nullptr, 4096, 3072, 1024);
    prep_kernel<<<dim3(32, 32), blk, 0, stream>>>(qkvb, ctab, stab, Qb, Kb, Vimg);
    attn32_kernel<<<dim3(1024), blk, 0, stream>>>(Qb, Kb, Vimg, po, pl);
    attn_combine_kernel<<<dim3(4096), blk, 0, stream>>>(po, pl, aob);
    gemm_bt_mfma<0><<<dim3(8, 32), blk, 0, stream>>>(aob, WoutT, out, bout, 4096, 1024, 1024);
}